// Round 8
// baseline (3212.835 us; speedup 1.0000x reference)
//
#include <hip/hip_runtime.h>
#include <hip/hip_bf16.h>

// SAGEClassifier: h[50000,256] --conv1(LSTM-agg)--> h1[50000,128] --conv2--> h2[50000,128]
//   --segment_max(256 graphs)--> hg[256,128] --linear--> out[256,10]
//
// Round 8: the LSTM's 2x __syncthreads()/iter each emit s_waitcnt vmcnt(0) -> the
// "prefetched" gathers were force-drained every iteration (why r3/r6/r7 all sat at
// ~2.3ms regardless of pipelining). Replace in-loop barriers with raw s_barrier +
// lgkmcnt(0)-only (LDS visibility); gathers now genuinely stay in flight across an
// iteration (PUB gets a counted vmcnt from the compiler).
// Also: launch_bounds minw=3 (conv1; LDS caps at 3 blocks/CU anyway) so the
// compiler allocates ~170 VGPRs instead of spilling to reach an unusable 4-wave cap.

#define NNODES  50000
#define DEG     16
#define INDIM   256
#define HIDDIM  128
#define NCLS    10
#define NGRAPH  256

typedef __hip_bfloat16 bf16;
typedef short bf16x8 __attribute__((ext_vector_type(8)));
typedef float f32x4  __attribute__((ext_vector_type(4)));

__device__ __forceinline__ float sigf(float x) {
    float e = __builtin_amdgcn_exp2f(-1.44269504f * x);
    return __builtin_amdgcn_rcpf(1.0f + e);
}
__device__ __forceinline__ float tanhf_(float x) {
    x = fminf(fmaxf(x, -10.f), 10.f);
    float e = __builtin_amdgcn_exp2f(2.88539008f * x);
    return (e - 1.0f) * __builtin_amdgcn_rcpf(e + 1.0f);
}
__device__ __forceinline__ float b2f(unsigned short u) {
    return __uint_as_float(((unsigned)u) << 16);
}
__device__ __forceinline__ unsigned short f2b(float f) {  // RNE bf16
    unsigned u = __float_as_uint(f);
    return (unsigned short)((u + 0x7FFF + ((u >> 16) & 1)) >> 16);
}

// Barrier with LDS-visibility only: does NOT drain vmcnt (in-flight global gathers
// survive). Memory clobber orders all surrounding memory ops; sched_barrier pins
// register-only ops (rule #18).
__device__ __forceinline__ void bar_lgkm() {
    __builtin_amdgcn_sched_barrier(0);
    asm volatile("s_waitcnt lgkmcnt(0)" ::: "memory");
    __builtin_amdgcn_s_barrier();
    __builtin_amdgcn_sched_barrier(0);
}

__global__ void f2bf_k(const float* __restrict__ in, unsigned short* __restrict__ out, int n) {
    int i = blockIdx.x * 256 + threadIdx.x;
    if (i < n) out[i] = f2b(in[i]);
}

// Pack W_hh [4D,D] fp32 -> per-(g,dc,wid,kk) contiguous 512-short bf16 chunks
__global__ void packw_k(const float* __restrict__ W, unsigned short* __restrict__ out,
                        int D, int ksh, int dsh) {
    int o = blockIdx.x * 256 + threadIdx.x;
    if (o >= 4 * D * D) return;
    int j  = o & 7;
    int lg = (o >> 3) & 3;
    int lr = (o >> 5) & 15;
    int cch = o >> 9;
    int kk = cch & ((1 << ksh) - 1);
    int c2 = cch >> ksh;
    int wd = c2 & 3;
    int c3 = c2 >> 2;
    int dc = c3 & ((1 << dsh) - 1);
    int g  = c3 >> dsh;
    out[o] = f2b(W[(g * D + dc * 64 + wd * 16 + lr) * D + kk * 32 + lg * 8 + j]);
}

// Pack B [N,K] fp32 -> per-(jt,kk) contiguous 512-short bf16 fragment chunks.
__global__ void packb_k(const float* __restrict__ B, unsigned short* __restrict__ out,
                        int N, int K, int ksh) {
    int o = blockIdx.x * 256 + threadIdx.x;
    if (o >= N * K) return;
    int j  = o & 7;
    int lg = (o >> 3) & 3;
    int lr = (o >> 5) & 15;
    int c  = o >> 9;
    int kk = c & ((1 << ksh) - 1);
    int jt = c >> ksh;
    out[o] = f2b(B[(jt * 16 + lr) * K + kk * 32 + lg * 8 + j]);
}

// ---------------- MFMA bf16 GEMM: C = A·B^T (+A2·B2^T) + bias, opt relu ----------------
template<bool RELU, bool DUAL, bool BF16OUT>
__global__ __launch_bounds__(256) void gemm_mfma(
    const unsigned short* __restrict__ A,  const unsigned short* __restrict__ Bp,
    const unsigned short* __restrict__ A2, const unsigned short* __restrict__ B2p,
    const float* __restrict__ bias0, const float* __restrict__ bias1,
    void* __restrict__ Cout, int M, int Ncol, int K, int K2, int ksh, int ksh2)
{
    __shared__ unsigned short As[64 * 72];   // [64][64+8] bf16
    const int tid  = threadIdx.x;
    const int wid  = tid >> 6;
    const int lane = tid & 63;
    const int lg   = lane >> 4;
    const int lr   = lane & 15;
    const int m0 = blockIdx.y * 64;
    const int j0 = blockIdx.x * 64;
    const int jt = (j0 >> 4) + wid;

    f32x4 acc[4];
    #pragma unroll
    for (int m = 0; m < 4; ++m)
        #pragma unroll
        for (int r = 0; r < 4; ++r) acc[m][r] = 0.f;

    const int npass = DUAL ? 2 : 1;
    for (int pass = 0; pass < npass; ++pass) {
        const unsigned short* Ap  = (DUAL && pass) ? A2  : A;
        const unsigned short* Bpp = (DUAL && pass) ? B2p : Bp;
        const int Kp   = (DUAL && pass) ? K2   : K;
        const int kshp = (DUAL && pass) ? ksh2 : ksh;
        for (int k0 = 0; k0 < Kp; k0 += 64) {
            __syncthreads();   // prev tile consumed
            #pragma unroll
            for (int p = 0; p < 2; ++p) {
                int i = tid + p * 256;
                int row = i >> 3, c16 = i & 7;
                uint4 v = make_uint4(0u, 0u, 0u, 0u);
                if (m0 + row < M) v = *(const uint4*)&Ap[(size_t)(m0 + row) * Kp + k0 + c16 * 8];
                *(uint4*)&As[row * 72 + c16 * 8] = v;
            }
            __syncthreads();
            #pragma unroll
            for (int kk = 0; kk < 2; ++kk) {
                bf16x8 b = *(const bf16x8*)&Bpp[(size_t)((jt << kshp) + (k0 >> 5) + kk) * 512 + lr * 32 + lg * 8];
                #pragma unroll
                for (int m = 0; m < 4; ++m) {
                    bf16x8 a = *(const bf16x8*)&As[(m * 16 + lr) * 72 + kk * 32 + lg * 8];
                    acc[m] = __builtin_amdgcn_mfma_f32_16x16x32_bf16(a, b, acc[m], 0, 0, 0);
                }
            }
        }
    }
    #pragma unroll
    for (int m = 0; m < 4; ++m)
        #pragma unroll
        for (int r = 0; r < 4; ++r) {
            int row = m0 + m * 16 + lg * 4 + r;
            if (row >= M) continue;
            int col = j0 + wid * 16 + lr;
            float v = acc[m][r];
            if (bias0) v += bias0[col];
            if (bias1) v += bias1[col];
            if (RELU) v = fmaxf(v, 0.f);
            if (BF16OUT) ((unsigned short*)Cout)[(size_t)row * Ncol + col] = f2b(v);
            else         ((float*)Cout)[(size_t)row * Ncol + col] = v;
        }
}

// ---------------- pipelined MFMA fused LSTM ----------------
// 32 nodes/block, 4 waves. Wave w owns d-cols [w*16,w*16+16) of each 64-chunk, all 4
// gates -> i/f/g/o of a (node,d) share a lane+reg. 2-deep gather pipeline; staging in
// 8 NAMED uint4 regs; in-loop barriers are lgkmcnt-only (gathers stay in flight).

#define ISSUE_M(s0, s1, s2, s3, tt, dd)                                                        \
    {                                                                                          \
        s0 = *(const uint4*)&Hin[(size_t)nidS[(srow     ) * DEG + (tt)] * FD + sg * D + (dd) * 64 + sc8 * 8]; \
        s1 = *(const uint4*)&Hin[(size_t)nidS[(srow +  8) * DEG + (tt)] * FD + sg * D + (dd) * 64 + sc8 * 8]; \
        s2 = *(const uint4*)&Hin[(size_t)nidS[(srow + 16) * DEG + (tt)] * FD + sg * D + (dd) * 64 + sc8 * 8]; \
        s3 = *(const uint4*)&Hin[(size_t)nidS[(srow + 24) * DEG + (tt)] * FD + sg * D + (dd) * 64 + sc8 * 8]; \
    }
#define PUB_M(s0, s1, s2, s3)                                      \
    {                                                              \
        *(uint4*)&hinS[(srow     ) * LDH + slot * 8] = s0;         \
        *(uint4*)&hinS[(srow +  8) * LDH + slot * 8] = s1;         \
        *(uint4*)&hinS[(srow + 16) * LDH + slot * 8] = s2;         \
        *(uint4*)&hinS[(srow + 24) * LDH + slot * 8] = s3;         \
    }

template<int D, int MINW>
__global__ __launch_bounds__(256, MINW) void lstm_mfma(
    const unsigned short* __restrict__ Hin,   // [Nn,4D] bf16 (bias folded)
    const unsigned short* __restrict__ Wbp,   // packed W_hh (packw_k)
    const int* __restrict__ nidx,             // [Nn,DEG]
    unsigned short* __restrict__ hout,        // [Nn,D] bf16
    int Nn)
{
    constexpr int FD  = 4 * D;
    constexpr int KCH = D / 32;
    constexpr int DCH = D / 64;
    constexpr int TN  = 32;
    constexpr int MT  = 2;
    constexpr int LDA = D + 8;
    constexpr int LDH = 264;
    constexpr int GST = DCH * 4 * KCH * 512;
    constexpr int NIT = DEG * DCH;

    __shared__ unsigned short hS[2][TN * LDA];   // dbuf h_state
    __shared__ unsigned short hinS[TN * LDH];    // gathered Hin slice (single buf)
    __shared__ int nidS[TN * DEG];

    const int tid  = threadIdx.x;
    const int wid  = tid >> 6;
    const int lane = tid & 63;
    const int lg   = lane >> 4;
    const int lr   = lane & 15;
    const int nb   = blockIdx.x * TN;
    const int srow = tid >> 5;    // staging base row (0..7)
    const int slot = tid & 31;    // 16B slot within 512B slice
    const int sg   = slot >> 3;   // gate
    const int sc8  = slot & 7;

    for (int i = tid; i < TN * DEG; i += 256) {
        int node = nb + (i >> 4);
        nidS[i] = (node < Nn) ? nidx[node * DEG + (i & 15)] : 0;
    }

    // identity B-fragment: B[col=lr][k=lg*8+j] = (lg*8+j == lr)
    bf16x8 bI;
    #pragma unroll
    for (int j = 0; j < 8; ++j)
        bI[j] = (short)((lg * 8 + j == lr) ? 0x3F80 : 0);

    float c[DCH][MT][4] = {};               // static indexing only (rule #20)
    uint4 sA0, sA1, sA2, sA3;               // named staging regs (never address-taken)
    uint4 sB0, sB1, sB2, sB3;

    __syncthreads();                        // nidS ready
    ISSUE_M(sA0, sA1, sA2, sA3, 0, 0)       // G0
    ISSUE_M(sB0, sB1, sB2, sB3, 0, 1)       // G1 (DCH>=2 always)
    PUB_M(sA0, sA1, sA2, sA3)               // waits only G0 (G1 younger in FIFO)
    __syncthreads();

    int cur = 0;
    #pragma unroll 1
    for (int t = 0; t < DEG; ++t) {
        #pragma unroll
        for (int dc = 0; dc < DCH; ++dc) {
            const int ii = t * DCH + dc;

            // ---- acc init from hinS (holds G_ii) via identity MFMA ----
            f32x4 acc[4][MT];
            #pragma unroll
            for (int g = 0; g < 4; ++g)
                #pragma unroll
                for (int m = 0; m < MT; ++m) {
                    #pragma unroll
                    for (int r = 0; r < 4; ++r) acc[g][m][r] = 0.f;
                    bf16x8 aI = *(const bf16x8*)&hinS[(m * 16 + lr) * LDH + g * 64 + wid * 16 + (lg & 1) * 8];
                    acc[g][m] = __builtin_amdgcn_mfma_f32_16x16x32_bf16(aI, bI, acc[g][m], 0, 0, 0);
                }
            bar_lgkm();   // all waves done reading hinS (lgkm only; gathers in flight)

            // ---- recurrent GEMM (packed W, coalesced 1KB chunks, L2-resident) ----
            if (t > 0) {
                const unsigned short* wb = Wbp + ((size_t)dc * 4 + wid) * KCH * 512 + lr * 32 + lg * 8;
                #pragma unroll
                for (int kk = 0; kk < KCH; ++kk) {
                    bf16x8 b[4];
                    #pragma unroll
                    for (int g = 0; g < 4; ++g)
                        b[g] = *(const bf16x8*)&wb[g * GST + kk * 512];
                    #pragma unroll
                    for (int m = 0; m < MT; ++m) {
                        bf16x8 a = *(const bf16x8*)&hS[cur][(m * 16 + lr) * LDA + kk * 32 + lg * 8];
                        #pragma unroll
                        for (int g = 0; g < 4; ++g)
                            acc[g][m] = __builtin_amdgcn_mfma_f32_16x16x32_bf16(a, b[g], acc[g][m], 0, 0, 0);
                    }
                }
            }

            // ---- issue G_{ii+2} (after W-loads: FIFO keeps W waits gather-free) ----
            if (ii + 2 < NIT) {
                const int t2 = (dc + 2 >= DCH) ? t + 1 : t;
                if (dc & 1) { ISSUE_M(sB0, sB1, sB2, sB3, t2, (dc + 2) % DCH) }
                else        { ISSUE_M(sA0, sA1, sA2, sA3, t2, (dc + 2) % DCH) }
            }

            // ---- LSTM nonlinearity; h_new -> hS[cur^1] (or hout bf16) ----
            #pragma unroll
            for (int m = 0; m < MT; ++m)
                #pragma unroll
                for (int r = 0; r < 4; ++r) {
                    float ig = sigf(acc[0][m][r]);
                    float fg = sigf(acc[1][m][r]);
                    float gg = tanhf_(acc[2][m][r]);
                    float og = sigf(acc[3][m][r]);
                    float cv = fmaf(fg, c[dc][m][r], ig * gg);
                    c[dc][m][r] = cv;
                    float hv = og * tanhf_(cv);
                    if (t < DEG - 1) {
                        hS[cur ^ 1][(m * 16 + lg * 4 + r) * LDA + dc * 64 + wid * 16 + lr] = f2b(hv);
                    } else {
                        int node = nb + m * 16 + lg * 4 + r;
                        if (node < Nn)
                            hout[(size_t)node * D + dc * 64 + wid * 16 + lr] = f2b(hv);
                    }
                }

            // ---- publish G_{ii+1} (compiler emits counted vmcnt: only 4 older loads) ----
            if (ii + 1 < NIT) {
                if ((dc + 1) & 1) { PUB_M(sB0, sB1, sB2, sB3) }
                else              { PUB_M(sA0, sA1, sA2, sA3) }
            }
            bar_lgkm();   // hinS + hS writes visible; vmcnt NOT drained
        }
        cur ^= 1;
    }
}

// ---------------- readout ----------------
__global__ void segmax_k(const unsigned short* __restrict__ h2, const int* __restrict__ gid,
                         float* __restrict__ hg, int Nn) {
    int g = blockIdx.x;
    int d = threadIdx.x;   // 128
    __shared__ int sb[2];
    if (d < 2) {
        int target = g + d;
        int lo = 0, hi = Nn;
        while (lo < hi) { int mid = (lo + hi) >> 1; if (gid[mid] < target) lo = mid + 1; else hi = mid; }
        sb[d] = lo;
    }
    __syncthreads();
    int lo = sb[0], hi = sb[1];
    float m = -INFINITY;
    for (int r = lo; r < hi; ++r) m = fmaxf(m, b2f(h2[(size_t)r * HIDDIM + d]));
    hg[g * HIDDIM + d] = m;
}

__global__ void cls_k(const float* __restrict__ hg, const float* __restrict__ W,
                      const float* __restrict__ b, float* __restrict__ out) {
    int idx = blockIdx.x * 256 + threadIdx.x;
    if (idx >= NGRAPH * NCLS) return;
    int g = idx / NCLS, cc = idx % NCLS;
    float s = b[cc];
    const float* hp = hg + g * HIDDIM;
    const float* wp = W + cc * HIDDIM;
    #pragma unroll 8
    for (int k = 0; k < HIDDIM; ++k) s = fmaf(hp[k], wp[k], s);
    out[idx] = s;
}

extern "C" void kernel_launch(void* const* d_in, const int* in_sizes, int n_in,
                              void* d_out, int out_size, void* d_ws, size_t ws_size,
                              hipStream_t stream)
{
    const float* h       = (const float*)d_in[0];
    const int*   nidx    = (const int*)d_in[1];
    const int*   gids    = (const int*)d_in[2];
    const float* W_ih1   = (const float*)d_in[3];
    const float* W_hh1   = (const float*)d_in[4];
    const float* b_ih1   = (const float*)d_in[5];
    const float* b_hh1   = (const float*)d_in[6];
    const float* W_self1 = (const float*)d_in[7];
    const float* W_neigh1= (const float*)d_in[8];
    const float* b1      = (const float*)d_in[9];
    const float* W_ih2   = (const float*)d_in[10];
    const float* W_hh2   = (const float*)d_in[11];
    const float* b_ih2   = (const float*)d_in[12];
    const float* b_hh2   = (const float*)d_in[13];
    const float* W_self2 = (const float*)d_in[14];
    const float* W_neigh2= (const float*)d_in[15];
    const float* b2      = (const float*)d_in[16];
    const float* W_cls   = (const float*)d_in[17];
    const float* b_cls   = (const float*)d_in[18];
    float* out = (float*)d_out;

    // ws layout (bf16 activations)
    char* ws = (char*)d_ws;
    unsigned short* Hin   = (unsigned short*)(ws);             // 102,400,000
    unsigned short* hb    = (unsigned short*)(ws + 102400000); //  25,600,000
    unsigned short* hnb   = (unsigned short*)(ws + 128000000); //  25,600,000 (lstm out)
    unsigned short* h1b   = (unsigned short*)(ws + 153600000); //  12,800,000
    unsigned short* h2b   = (unsigned short*)(ws + 166400000); //  12,800,000
    float*          hg    = (float*)(ws + 179200000);          //     131,072
    unsigned short* Whh1p = (unsigned short*)(ws + 179331072); //     524,288
    unsigned short* Whh2p = (unsigned short*)(ws + 179855360); //     131,072
    unsigned short* Wih1p = (unsigned short*)(ws + 179986432); //     524,288
    unsigned short* Wih2p = (unsigned short*)(ws + 180510720); //     131,072
    unsigned short* Wsl1p = (unsigned short*)(ws + 180641792); //      65,536
    unsigned short* Wng1p = (unsigned short*)(ws + 180707328); //      65,536
    unsigned short* Wsl2p = (unsigned short*)(ws + 180772864); //      32,768
    unsigned short* Wng2p = (unsigned short*)(ws + 180805632); //      32,768

    // prep: conversions + packing (all tiny)
    f2bf_k<<<dim3(50000), 256, 0, stream>>>(h, hb, NNODES * INDIM);
    packw_k<<<dim3(1024), 256, 0, stream>>>(W_hh1, Whh1p, 256, 3, 2);
    packw_k<<<dim3(256), 256, 0, stream>>>(W_hh2, Whh2p, 128, 2, 1);
    packb_k<<<dim3(1024), 256, 0, stream>>>(W_ih1, Wih1p, 1024, 256, 3);
    packb_k<<<dim3(256), 256, 0, stream>>>(W_ih2, Wih2p, 512, 128, 2);
    packb_k<<<dim3(128), 256, 0, stream>>>(W_self1, Wsl1p, 128, 256, 3);
    packb_k<<<dim3(128), 256, 0, stream>>>(W_neigh1, Wng1p, 128, 256, 3);
    packb_k<<<dim3(64), 256, 0, stream>>>(W_self2, Wsl2p, 128, 128, 2);
    packb_k<<<dim3(64), 256, 0, stream>>>(W_neigh2, Wng2p, 128, 128, 2);

    const int MB = (NNODES + 63) / 64;     // 782
    const int NB32 = (NNODES + 31) / 32;   // 1563

    // ---- conv1 ----
    gemm_mfma<false, false, true><<<dim3(1024 / 64, MB), 256, 0, stream>>>(
        hb, Wih1p, nullptr, nullptr, b_ih1, b_hh1, Hin, NNODES, 1024, 256, 0, 3, 0);
    lstm_mfma<256, 3><<<dim3(NB32), 256, 0, stream>>>(Hin, Whh1p, nidx, hnb, NNODES);
    gemm_mfma<true, true, true><<<dim3(HIDDIM / 64, MB), 256, 0, stream>>>(
        hb, Wsl1p, hnb, Wng1p, b1, nullptr, h1b, NNODES, HIDDIM, 256, 256, 3, 3);

    // ---- conv2 ----
    gemm_mfma<false, false, true><<<dim3(512 / 64, MB), 256, 0, stream>>>(
        h1b, Wih2p, nullptr, nullptr, b_ih2, b_hh2, Hin, NNODES, 512, 128, 0, 2, 0);
    lstm_mfma<128, 4><<<dim3(NB32), 256, 0, stream>>>(Hin, Whh2p, nidx, hnb, NNODES);
    gemm_mfma<true, true, true><<<dim3(HIDDIM / 64, MB), 256, 0, stream>>>(
        h1b, Wsl2p, hnb, Wng2p, b2, nullptr, h2b, NNODES, HIDDIM, 128, 128, 2, 2);

    // ---- readout ----
    segmax_k<<<dim3(NGRAPH), 128, 0, stream>>>(h2b, gids, hg, NNODES);
    cls_k<<<dim3((NGRAPH * NCLS + 255) / 256), 256, 0, stream>>>(hg, W_cls, b_cls, out);
}